// Round 3
// baseline (578.149 us; speedup 1.0000x reference)
//
#include <hip/hip_runtime.h>

#define NN 16384
#define QOFF ((size_t)NN * 512)   // float offset of index_k in out
#define WOFF ((size_t)NN * 640)   // float offset of weights in out
#define NQU  (NN * 4)             // 65536 q-units (token,group)
#define TOTALU (NQU + NN)         // + 16384 k-units (token)
#define QK_BLOCKS 1024
#define NWAVES (QK_BLOCKS * 4)    // 4096 waves -> exactly 20 units each

// fold inverse (verified R1): d = 4*(n&15) + (n>>4) + 2*jb + 64*im
//   q: head = jj*4 + group ; k: row g = jj ; j = jb*8 + jj
// Wave-autonomous: each wave stages its unit's 8 rows (4 KB) into a private
// LDS slab (no __syncthreads anywhere), transposes via LDS, computes 128
// outputs. Register double-buffer overlaps next unit's HBM loads w/ compute.

__global__ __launch_bounds__(256, 4) void qk_kernel(
    const float* __restrict__ q, const float* __restrict__ k,
    const float* __restrict__ proj, float* __restrict__ out)
{
    __shared__ float sq[4][1024];          // one 4 KB slab per wave
    const int tid = threadIdx.x;
    const int wv  = tid >> 6;
    const int l   = tid & 63;
    const int jj  = l >> 3;                // staging row 0..7
    const int m   = l & 7;                 // staging 16B-chunk 0..7
    const int im  = l >> 5;
    const int n   = l & 31;
    const int dloc = (n & 15) * 4 + (n >> 4) + im * 64;

    // proj row n -> 32 registers, loaded once per wave (persistent reuse)
    float pr[32];
    {
        const float4* p4 = (const float4*)proj;
        #pragma unroll
        for (int c = 0; c < 8; ++c) {
            const float4 t = p4[n * 8 + c];
            pr[c*4+0] = t.x; pr[c*4+1] = t.y; pr[c*4+2] = t.z; pr[c*4+3] = t.w;
        }
    }

    const int w = blockIdx.x * 4 + wv;     // global wave id
    float4* slds = (float4*)sq[wv];

    // prefetch unit w
    float4 buf[4];
    {
        const float4* src; int rs4;
        if (w < NQU) { src = (const float4*)(q + (size_t)(w>>2)*4096 + (w&3)*128); rs4 = 128; }
        else         { src = (const float4*)(k + (size_t)(w - NQU)*1024);          rs4 = 32;  }
        #pragma unroll
        for (int i = 0; i < 4; ++i) buf[i] = src[jj*rs4 + m + 8*i];
    }

    for (int u = w; u < TOTALU; u += NWAVES) {
        __builtin_amdgcn_wave_barrier();   // WAR: prior ds_reads stay before these writes
        #pragma unroll
        for (int i = 0; i < 4; ++i) slds[jj*32 + m + 8*i] = buf[i];

        // issue next unit's loads (single-slack pipeline)
        const int un = u + NWAVES;
        if (un < TOTALU) {
            const float4* src; int rs4;
            if (un < NQU) { src = (const float4*)(q + (size_t)(un>>2)*4096 + (un&3)*128); rs4 = 128; }
            else          { src = (const float4*)(k + (size_t)(un - NQU)*1024);           rs4 = 32;  }
            #pragma unroll
            for (int i = 0; i < 4; ++i) buf[i] = src[jj*rs4 + m + 8*i];
        }
        __builtin_amdgcn_wave_barrier();   // RAW: ds_reads stay after ds_writes

        const float* s = sq[wv];
        float a0 = 0.f, a1 = 0.f;
        #pragma unroll
        for (int j8 = 0; j8 < 8; ++j8) {
            const float v0 = s[j8*128 + dloc];       // j = j8      (jb=0)
            const float v1 = s[j8*128 + dloc + 2];   // j = 8 + j8  (jb=1)
            a0 += v0 * pr[2*j8];        a1 += v0 * pr[2*j8 + 1];
            a0 += v1 * pr[16 + 2*j8];   a1 += v1 * pr[16 + 2*j8 + 1];
        }
        float* ob;
        if (u < NQU) ob = out + (size_t)(u>>2)*512 + (u&3)*128;
        else         ob = out + QOFF + (size_t)(u - NQU)*128;
        *(float2*)(ob + im*64 + n*2) = make_float2(a0, a1);
    }
}

// weights kernel: 4 tokens/block, proven R1 phase-3 logic
__global__ void vw_kernel(const float* __restrict__ v,
                          const float* __restrict__ vt,
                          float* __restrict__ out)
{
    __shared__ float sv[4096];
    __shared__ float sw[4][32];
    const int b0 = blockIdx.x * 4;
    const int tid = threadIdx.x;
    {
        const float4* v4 = (const float4*)(v + (size_t)b0 * 1024);
        float4* s4 = (float4*)sv;
        #pragma unroll
        for (int i = 0; i < 4; ++i) s4[tid + 256*i] = v4[tid + 256*i];
    }
    __syncthreads();
    const int h = tid >> 3, s = tid & 7, g = h >> 2;
    const float4* vt4 = (const float4*)vt;   // [H][D] float4 over R
    float4 acc[4];
    #pragma unroll
    for (int t = 0; t < 4; ++t) acc[t] = make_float4(0.f, 0.f, 0.f, 0.f);
    #pragma unroll
    for (int i = 0; i < 16; ++i) {
        const int d = i*8 + s;
        const float4 w4 = vt4[h*128 + d];
        #pragma unroll
        for (int t = 0; t < 4; ++t) {
            const float vv = sv[t*1024 + g*128 + d];  // 4-lane broadcast, conflict-free
            acc[t].x += vv*w4.x; acc[t].y += vv*w4.y;
            acc[t].z += vv*w4.z; acc[t].w += vv*w4.w;
        }
    }
    #pragma unroll
    for (int t = 0; t < 4; ++t) {
        #pragma unroll
        for (int off = 4; off >= 1; off >>= 1) {
            acc[t].x += __shfl_down(acc[t].x, off, 8);
            acc[t].y += __shfl_down(acc[t].y, off, 8);
            acc[t].z += __shfl_down(acc[t].z, off, 8);
            acc[t].w += __shfl_down(acc[t].w, off, 8);
        }
        if (s == 0)
            sw[t][h] = acc[t].x*acc[t].x + acc[t].y*acc[t].y
                     + acc[t].z*acc[t].z + acc[t].w*acc[t].w;
    }
    __syncthreads();
    if (tid < 16) {
        const int t = tid >> 2, grp = tid & 3;
        float a = 0.f;
        #pragma unroll
        for (int g8 = 0; g8 < 8; ++g8) a += sw[t][g8*4 + grp];
        out[WOFF + (size_t)(b0 + t)*4 + grp] = sqrtf(a);
    }
}

extern "C" void kernel_launch(void* const* d_in, const int* in_sizes, int n_in,
                              void* d_out, int out_size, void* d_ws, size_t ws_size,
                              hipStream_t stream) {
    const float* q    = (const float*)d_in[0];
    const float* k    = (const float*)d_in[1];
    const float* v    = (const float*)d_in[2];
    const float* proj = (const float*)d_in[3];
    const float* vt   = (const float*)d_in[4];
    float* out = (float*)d_out;
    qk_kernel<<<QK_BLOCKS, 256, 0, stream>>>(q, k, proj, out);
    vw_kernel<<<NN/4, 256, 0, stream>>>(v, vt, out);
}